// Round 11
// baseline (671.266 us; speedup 1.0000x reference)
//
#include <hip/hip_runtime.h>

#define NQ 8192
#define CD 128
#define NB 2
#define KNN 20
#define QB 16    // queries per block -> 1024 blocks
#define TB 128   // candidates per tile (LDS-staged, hi only)
#define LDC 136  // chi row stride in f16 elems (+8 pad)
#define M 8      // per-lane top-M list (32 lanes/query; overflow P ~ 2.5e-3 total)
#define NSEL 32  // merged shortlist for exact re-rank
#define LOSCALE 4096.0f
#define LOINV (1.0f / 4096.0f)

using f16x8 = __attribute__((ext_vector_type(8))) _Float16;
using f16x2 = __attribute__((ext_vector_type(2))) _Float16;
using f32x4 = __attribute__((ext_vector_type(4))) float;

// ---------------- transpose (B,C,N) f32 -> (B,N,C) split f16 hi + scaled lo ----------------
__global__ __launch_bounds__(256) void k_transpose(const float* __restrict__ x,
                                                   _Float16* __restrict__ vhi,
                                                   _Float16* __restrict__ vlo) {
  __shared__ float tile[32][33];
  int bid = blockIdx.x;
  int ctile = bid & 3;            // CD/32 = 4
  int ntile = (bid >> 2) & 255;   // NQ/32 = 256
  int b = bid >> 10;
  int c0 = ctile << 5, n0 = ntile << 5;
  int tx = threadIdx.x & 31, ty = threadIdx.x >> 5;  // ty 0..7
  const float* xb = x + (size_t)b * CD * NQ;
  _Float16* hb = vhi + (size_t)b * NQ * CD;
  _Float16* lb = vlo + (size_t)b * NQ * CD;
#pragma unroll
  for (int i = 0; i < 4; ++i) {
    int c = ty + (i << 3);
    tile[c][tx] = xb[(size_t)(c0 + c) * NQ + n0 + tx];
  }
  __syncthreads();
#pragma unroll
  for (int i = 0; i < 4; ++i) {
    int n = ty + (i << 3);
    float v = tile[tx][n];
    _Float16 h = (_Float16)v;
    float hf = (float)h;
    _Float16 l = (_Float16)((v - hf) * LOSCALE);  // exact pow2 scale keeps lo normal
    size_t o = (size_t)(n0 + n) * CD + c0 + tx;
    hb[o] = h;
    lb[o] = l;
  }
}

// ---------------- per-row sum of squares (reads x in (B,C,N), coalesced) ----------------
__global__ __launch_bounds__(256) void k_xx(const float* __restrict__ x,
                                            float* __restrict__ xx) {
  int n = blockIdx.x * 256 + threadIdx.x;
  int b = blockIdx.y;
  const float* xb = x + (size_t)b * CD * NQ + n;
  float s = 0.f;
#pragma unroll
  for (int c = 0; c < CD; ++c) {
    float v = xb[(size_t)c * NQ];
    s += v * v;
  }
  xx[(size_t)b * NQ + n] = s;
}

// ---------------- knn: LDS-staged swapped MFMA + per-lane top-M + exact re-rank -------------
// 1024 blocks (512 q-blocks/batch), 512 threads (8 waves).
// Stage tile (hi only, coalesced); wave w MFMAs its 16-cand subtile vs the block's
// 16 queries (B-frags in regs): D[cand=(lane>>4)*4+r][query=lane&15] -> each lane
// owns query lane&15 with 4 cand scores/tile IN REGISTERS. Selection = per-lane
// in-place bubble top-M (pure VALU, no temp arrays, no cross-lane ops).
// Epilogue (r9/r10-proven): dump 32xM per query -> LDS (aliased over chi),
// ballot-walk top-32, exact hi+lo re-rank, bitonic sort, write top-20.
__global__ __launch_bounds__(512) void k_knn(const _Float16* __restrict__ vhi,
                                             const _Float16* __restrict__ vlo,
                                             const float* __restrict__ xx,
                                             int* __restrict__ idxout) {
  __shared__ char ubuf[TB * LDC * 2];        // 34816 B: chi[128][136] f16; epilogue mg alias
  auto chi = (_Float16(*)[LDC])ubuf;
  float (*mg_d)[32][M] = (float(*)[32][M])ubuf;                   // 8*32*M*4 = 8192 B
  int (*mg_i)[32][M] = (int(*)[32][M])(ubuf + 8 * 32 * M * 4);    // +8192 = 16384 <= 34816

  const int t = threadIdx.x;
  const int blk = blockIdx.x;
  const int b = blk >> 9;                 // 512 q-blocks per batch
  const int q0 = (blk & 511) * QB;
  const _Float16* hb = vhi + (size_t)b * NQ * CD;
  const _Float16* lb = vlo + (size_t)b * NQ * CD;
  const float* xb = xx + (size_t)b * NQ;

  const int lane = t & 63, w = t >> 6;
  const int qme = lane & 15;              // query this lane owns
  const int qg = q0 + qme;                // global query id (self-exclusion)
  const int kof = (lane >> 4) * 8;

  // persistent B fragments: query rows (hi only), loaded once from global
  f16x8 bq[4];
  {
    const _Float16* qrow = hb + (size_t)qg * CD + kof;
#pragma unroll
    for (int ks = 0; ks < 4; ++ks) bq[ks] = *(const f16x8*)(qrow + ks * 32);
  }

  // per-lane sorted top-M ascending; ld[M-1] is the running threshold
  float ld[M]; int li[M];
#pragma unroll
  for (int j = 0; j < M; ++j) { ld[j] = 3.0e38f; li[j] = 0; }

  const int sub0 = 16 * w;                // wave's cand subtile within the staged tile
  const int arow = sub0 + (lane & 15);

  for (int tile = 0; tile < NQ / TB; ++tile) {
    const int c0 = tile * TB;
    __syncthreads();  // B1: all waves done reading chi (prev tile)

    // stage candidate tile (hi only): 2048 chunks of 8 f16, coalesced
#pragma unroll
    for (int i = 0; i < 4; ++i) {
      int e = t + i * 512;
      int r = e >> 4, ch = (e & 15) * 8;
      *(f16x8*)&chi[r][ch] = *(const f16x8*)(hb + (size_t)(c0 + r) * CD + ch);
    }
    __syncthreads();  // B2: staged

    // swapped MFMA: A = cand subtile rows (LDS), B = query frags (regs)
    f32x4 acc = (f32x4){0.f, 0.f, 0.f, 0.f};
#pragma unroll
    for (int ks = 0; ks < 4; ++ks) {
      f16x8 a = *(const f16x8*)&chi[arow][ks * 32 + kof];
      acc = __builtin_amdgcn_mfma_f32_16x16x32_f16(a, bq[ks], acc, 0, 0, 0);
    }

    const int cbase = c0 + sub0 + (lane >> 4) * 4;
    float4 xc4 = *(const float4*)(xb + cbase);
    float xcr[4] = {xc4.x, xc4.y, xc4.z, xc4.w};

    // per-lane selection: rank-equivalent score s = xc - 2*dot (xq const per query)
#pragma unroll
    for (int r = 0; r < 4; ++r) {
      float s = fmaf(-2.0f, acc[r], xcr[r]);
      int ci = cbase + r;
      if (s < ld[M - 1] && ci != qg) {
        // in-place bubble insert: place at bottom, compare-swap upward (no temp arrays)
        ld[M - 1] = s; li[M - 1] = ci;
#pragma unroll
        for (int j = M - 1; j > 0; --j) {
          bool sw = ld[j] < ld[j - 1];
          float da = ld[j - 1], db = ld[j];
          int ia = li[j - 1], ib = li[j];
          ld[j - 1] = sw ? db : da; li[j - 1] = sw ? ib : ia;
          ld[j] = sw ? da : db;     li[j] = sw ? ia : ib;
        }
      }
    }
  }

  // ---------------- epilogue: merge + exact re-rank, 2 rounds x 8 queries ----------------
#pragma unroll 1
  for (int rd = 0; rd < 2; ++rd) {
    const int qlo = rd * 8;
    __syncthreads();  // rd0: main loop done with chi; rd1: prev round done with mg
    if (qme >= qlo && qme < qlo + 8) {
      int qq = qme - qlo, ls = w * 4 + (lane >> 4);
#pragma unroll
      for (int j = 0; j < M; ++j) { mg_d[qq][ls][j] = ld[j]; mg_i[qq][ls][j] = li[j]; }
    }
    __syncthreads();

    // wave w: merge 256 entries of query q0+qlo+w -> distributed top-32 (rank r in lane r)
    float wd[4]; int wi[4];
    {
      const float* pd = &mg_d[w][0][0];
      const int* pi = &mg_i[w][0][0];
#pragma unroll
      for (int j = 0; j < 4; ++j) { wd[j] = pd[lane * 4 + j]; wi[j] = pi[lane * 4 + j]; }
    }
    float ed = 3.0e38f; int ei = 0; float tau = 3.0e38f;
    int cnt = 0;
#pragma unroll 1
    for (int jj = 0; jj < 4; ++jj) {
      unsigned long long mk = __ballot(wd[jj] < tau);
      while (mk) {
        int l = __builtin_ctzll(mk); mk &= mk - 1;
        float d = __shfl(wd[jj], l);
        if (d < tau) {
          int ii = __shfl(wi[jj], l);
          float sh = __shfl_up(ed, 1);
          int shi = __shfl_up(ei, 1);
          bool cprev = (lane > 0) && (d < sh);
          bool ccur = d < ed;
          ed = ccur ? (cprev ? sh : d) : ed;
          ei = ccur ? (cprev ? shi : ii) : ei;
          if ((++cnt & 7) == 0) tau = __shfl(ed, NSEL - 1);
        }
      }
      tau = __shfl(ed, NSEL - 1);
    }

    // exact re-rank of the 32 survivors (lanes 32..63 duplicate harmlessly)
    const int r32 = lane & 31;
    const int qg2 = q0 + qlo + w;
    int ci = __shfl(ei, r32);
    const _Float16* qh = hb + (size_t)qg2 * CD;
    const _Float16* qlw = lb + (size_t)qg2 * CD;
    const _Float16* ch = hb + (size_t)ci * CD;
    const _Float16* cl = lb + (size_t)ci * CD;
    float dot = 0.f;
#pragma unroll
    for (int kc = 0; kc < CD / 8; ++kc) {
      f16x8 ah = *(const f16x8*)(qh + kc * 8);
      f16x8 al = *(const f16x8*)(qlw + kc * 8);
      f16x8 bh = *(const f16x8*)(ch + kc * 8);
      f16x8 bl = *(const f16x8*)(cl + kc * 8);
#pragma unroll
      for (int e = 0; e < 8; ++e) {
        float qv = fmaf((float)al[e], LOINV, (float)ah[e]);
        float cv = fmaf((float)bl[e], LOINV, (float)bh[e]);
        dot = fmaf(qv, cv, dot);
      }
    }
    float dex = (xb[qg2] + (-2.0f * dot)) + xb[ci];

    // bitonic sort 32 ascending by (dex, ci) within each 32-lane half
#pragma unroll
    for (int k = 2; k <= 32; k <<= 1) {
#pragma unroll
      for (int j2 = k >> 1; j2 >= 1; j2 >>= 1) {
        float od = __shfl_xor(dex, j2);
        int oi = __shfl_xor(ci, j2);
        bool lower = !(r32 & j2);
        bool up = ((r32 & k) == 0) || (k == 32);
        bool tt = (od < dex) || (od == dex && oi < ci);
        if (tt == (lower == up)) { dex = od; ci = oi; }
      }
    }
    if (lane < KNN)
      idxout[(size_t)(b * NQ + qg2) * KNN + lane] = ci;
  }
}

// ---------------- gather 20 neighbors (hi + lo/4096), max, write (B,C,N) ----------------
__global__ __launch_bounds__(256) void k_gather(const _Float16* __restrict__ vhi,
                                                const _Float16* __restrict__ vlo,
                                                const int* __restrict__ idx,
                                                float* __restrict__ out) {
  __shared__ float tile[CD][65];
  int blk = blockIdx.x;            // 256 blocks: 64 n's each
  int b = blk >> 7;
  int n0 = (blk & 127) * 64;
  int w = threadIdx.x >> 6, lane = threadIdx.x & 63;
  const _Float16* hb = vhi + (size_t)b * NQ * CD;
  const _Float16* lb = vlo + (size_t)b * NQ * CD;
  for (int s = 0; s < 16; ++s) {
    int nl = w * 16 + s;
    const int* id = idx + (size_t)(b * NQ + n0 + nl) * KNN;
    float ma = -3.0e38f, mb = -3.0e38f;  // cols 2*lane, 2*lane+1
#pragma unroll
    for (int j = 0; j < KNN; ++j) {
      size_t ro = (size_t)id[j] * CD + 2 * lane;
      f16x2 h = *(const f16x2*)(hb + ro);
      f16x2 l = *(const f16x2*)(lb + ro);
      ma = fmaxf(ma, fmaf((float)l[0], LOINV, (float)h[0]));
      mb = fmaxf(mb, fmaf((float)l[1], LOINV, (float)h[1]));
    }
    tile[2 * lane][nl] = ma;
    tile[2 * lane + 1][nl] = mb;
  }
  __syncthreads();
  float* ob = out + (size_t)b * CD * NQ;
  for (int i = 0; i < 32; ++i) {
    int e = threadIdx.x + i * 256;   // 128 c x 64 n
    int c = e >> 6, j = e & 63;
    ob[(size_t)c * NQ + n0 + j] = tile[c][j];
  }
}

extern "C" void kernel_launch(void* const* d_in, const int* in_sizes, int n_in,
                              void* d_out, int out_size, void* d_ws, size_t ws_size,
                              hipStream_t stream) {
  const float* x = (const float*)d_in[0];  // vertex_feat (B,C,N)
  size_t velems = (size_t)NB * NQ * CD;
  _Float16* vhi = (_Float16*)d_ws;                           // 4 MB
  _Float16* vlo = vhi + velems;                              // 4 MB
  float* xx = (float*)((char*)d_ws + velems * 4);            // 64 KB
  int* idx = (int*)((char*)xx + (size_t)NB * NQ * 4);        // 1.3 MB
  float* out = (float*)d_out;

  k_transpose<<<dim3(NB * 256 * 4), dim3(256), 0, stream>>>(x, vhi, vlo);
  k_xx<<<dim3(NQ / 256, NB), dim3(256), 0, stream>>>(x, xx);
  k_knn<<<dim3(NB * NQ / QB), dim3(512), 0, stream>>>(vhi, vlo, xx, idx);
  k_gather<<<dim3(NB * NQ / 64), dim3(256), 0, stream>>>(vhi, vlo, idx, out);
}

// Round 12
// 441.620 us; speedup vs baseline: 1.5200x; 1.5200x over previous
//
#include <hip/hip_runtime.h>

#define NQ 8192
#define CD 128
#define NB 2
#define KNN 20
#define QB 32    // queries per block -> 512 blocks (r4 champion frame)
#define TB 128   // candidates per tile (LDS-staged, hi only)
#define LDC 136  // chi row stride in f16 elems (+8 pad)
#define LDSD 132 // sd row stride in f32
#define NSEL 32  // approx shortlist length per query (then exact re-rank -> top-20)
#define LOSCALE 4096.0f
#define LOINV (1.0f / 4096.0f)

using f16x8 = __attribute__((ext_vector_type(8))) _Float16;
using f16x2 = __attribute__((ext_vector_type(2))) _Float16;
using f32x4 = __attribute__((ext_vector_type(4))) float;

// ---------------- transpose (B,C,N) f32 -> (B,N,C) split f16 hi + scaled lo ----------------
__global__ __launch_bounds__(256) void k_transpose(const float* __restrict__ x,
                                                   _Float16* __restrict__ vhi,
                                                   _Float16* __restrict__ vlo) {
  __shared__ float tile[32][33];
  int bid = blockIdx.x;
  int ctile = bid & 3;            // CD/32 = 4
  int ntile = (bid >> 2) & 255;   // NQ/32 = 256
  int b = bid >> 10;
  int c0 = ctile << 5, n0 = ntile << 5;
  int tx = threadIdx.x & 31, ty = threadIdx.x >> 5;  // ty 0..7
  const float* xb = x + (size_t)b * CD * NQ;
  _Float16* hb = vhi + (size_t)b * NQ * CD;
  _Float16* lb = vlo + (size_t)b * NQ * CD;
#pragma unroll
  for (int i = 0; i < 4; ++i) {
    int c = ty + (i << 3);
    tile[c][tx] = xb[(size_t)(c0 + c) * NQ + n0 + tx];
  }
  __syncthreads();
#pragma unroll
  for (int i = 0; i < 4; ++i) {
    int n = ty + (i << 3);
    float v = tile[tx][n];
    _Float16 h = (_Float16)v;
    float hf = (float)h;
    _Float16 l = (_Float16)((v - hf) * LOSCALE);  // exact pow2 scale keeps lo normal
    size_t o = (size_t)(n0 + n) * CD + c0 + tx;
    hb[o] = h;
    lb[o] = l;
  }
}

// ---------------- per-row sum of squares (reads x in (B,C,N), coalesced) ----------------
__global__ __launch_bounds__(256) void k_xx(const float* __restrict__ x,
                                            float* __restrict__ xx) {
  int n = blockIdx.x * 256 + threadIdx.x;
  int b = blockIdx.y;
  const float* xb = x + (size_t)b * CD * NQ + n;
  float s = 0.f;
#pragma unroll
  for (int c = 0; c < CD; ++c) {
    float v = xb[(size_t)c * NQ];
    s += v * v;
  }
  xx[(size_t)b * NQ + n] = s;
}

// ---------------- knn: r4 frame, hi-only approx top-32 + exact re-rank ----------------
// 512 blocks (256 q-blocks/batch), 512 threads (8 waves).
// Wave w: MFMA strip = q rows [16*(w&1),+16) x cand cols [32*(w>>1),+32) (hi only);
//          selection owns queries 4w..4w+3 over all 128 cols, 32-long list.
// LDS: ubuf = chi[128][136] f16 (34.8 KB, aliased by sd[32][132] f32 16.9 KB)
//      + xq/xc -> ~35.4 KB -> 4 blocks/CU at VGPR<=64.
// Epilogue: per wave, per query: exact hi+lo re-rank of the 32 survivors
// (dot loop unroll-LIMITED to keep register pressure low -> no spill), bitonic, top-20.
__global__ __launch_bounds__(512, 4) void k_knn(const _Float16* __restrict__ vhi,
                                                const _Float16* __restrict__ vlo,
                                                const float* __restrict__ xx,
                                                int* __restrict__ idxout) {
  __shared__ char ubuf[TB * LDC * 2];   // 34816 B: chi[128][136] f16; sd alias
  __shared__ float xq[QB];
  __shared__ float xc[TB];
  auto chi = (_Float16(*)[LDC])ubuf;
  auto sd = (float(*)[LDSD])ubuf;       // phases time-disjoint (r4-proven)

  const int t = threadIdx.x;
  const int blk = blockIdx.x;
  const int b = blk >> 8;
  const int q0 = (blk & 255) * QB;
  const _Float16* hb = vhi + (size_t)b * NQ * CD;
  const _Float16* lb = vlo + (size_t)b * NQ * CD;
  const float* xb = xx + (size_t)b * NQ;

  const int lane = t & 63, w = t >> 6;
  const int strip = w & 1;    // q-row strip (16 rows)
  const int quarter = w >> 1; // candidate col quarter (32 cols)

  if (t < QB) xq[t] = xb[q0 + t];

  // persistent A fragments (hi only): row = q0+16*strip+(lane&15), k = ks*32+(lane>>4)*8
  f16x8 ahi[4];
  {
    int row = q0 + 16 * strip + (lane & 15);
    int kof = (lane >> 4) * 8;
    const _Float16* hrow = hb + (size_t)row * CD + kof;
#pragma unroll
    for (int ks = 0; ks < 4; ++ks) ahi[ks] = *(const f16x8*)(hrow + ks * 32);
  }

  // approx top-32 state: 4 queries per wave; sorted ascending, rank r lives in lane r
  float ed[4]; int ei[4]; float tau[4];
#pragma unroll
  for (int u = 0; u < 4; ++u) { ed[u] = 3.0e38f; ei[u] = 0; tau[u] = 3.0e38f; }

  auto insert1 = [&](float& edu, int& eiu, float d, int ci) {
    float sh = __shfl_up(edu, 1);
    int shi = __shfl_up(eiu, 1);
    bool cprev = (lane > 0) && (d < sh);
    bool ccur = d < edu;
    edu = ccur ? (cprev ? sh : d) : edu;
    eiu = ccur ? (cprev ? shi : ci) : eiu;
  };

  for (int tile = 0; tile < NQ / TB; ++tile) {
    const int c0 = tile * TB;
    __syncthreads();  // B1: prev selection done with sd(=chi region)

    // stage candidate tile (hi only): 2048 chunks of 8 f16, coalesced
#pragma unroll
    for (int i = 0; i < 4; ++i) {
      int e = t + i * 512;
      int r = e >> 4, ch = (e & 15) * 8;
      *(f16x8*)&chi[r][ch] = *(const f16x8*)(hb + (size_t)(c0 + r) * CD + ch);
    }
    if (t < TB) xc[t] = xb[c0 + t];
    __syncthreads();  // B2: staged

    // MFMA: 2 fragments (16q x 32c), hi*hi only
    f32x4 accA[2];
    accA[0] = (f32x4){0.f, 0.f, 0.f, 0.f};
    accA[1] = (f32x4){0.f, 0.f, 0.f, 0.f};
    const int kof = (lane >> 4) * 8;
#pragma unroll
    for (int ks = 0; ks < 4; ++ks) {
#pragma unroll
      for (int f = 0; f < 2; ++f) {
        int c = 32 * quarter + 16 * f + (lane & 15);
        f16x8 bhi = *(const f16x8*)&chi[c][ks * 32 + kof];
        accA[f] = __builtin_amdgcn_mfma_f32_16x16x32_f16(ahi[ks], bhi, accA[f], 0, 0, 0);
      }
    }

    // approx distances to registers, then LDS after barrier (r4 pattern)
    float dv[2][4];
#pragma unroll
    for (int f = 0; f < 2; ++f) {
      int c = 32 * quarter + 16 * f + (lane & 15);
      float xcv = xc[c];
#pragma unroll
      for (int r = 0; r < 4; ++r) {
        int qrow = 16 * strip + (lane >> 4) * 4 + r;
        float tmp = xq[qrow] + (-2.0f * accA[f][r]);
        dv[f][r] = tmp + xcv;
      }
    }
    __syncthreads();  // B3: all waves done reading chi -> safe to overwrite with sd
#pragma unroll
    for (int f = 0; f < 2; ++f) {
      int c = 32 * quarter + 16 * f + (lane & 15);
#pragma unroll
      for (int r = 0; r < 4; ++r) {
        int qrow = 16 * strip + (lane >> 4) * 4 + r;
        sd[qrow][c] = dv[f][r];
      }
    }
    __syncthreads();  // B4: sd ready

    // selection: wave w owns queries 4w..4w+3 over all 128 cols (32-long lists)
#pragma unroll
    for (int u = 0; u < 4; ++u) {
      int q = 4 * w + u;
      int qg = q0 + q;
      float d0 = sd[q][lane];
      float d1 = sd[q][64 + lane];
      int cnt = 0;
      unsigned long long m0 = __ballot(d0 < tau[u] && (c0 + lane) != qg);
      while (m0) {
        int l = __builtin_ctzll(m0); m0 &= m0 - 1;
        float d = __shfl(d0, l);
        if (d < tau[u]) {
          insert1(ed[u], ei[u], d, c0 + l);
          if ((++cnt & 7) == 0) tau[u] = __shfl(ed[u], NSEL - 1);
        }
      }
      tau[u] = __shfl(ed[u], NSEL - 1);
      unsigned long long m1 = __ballot(d1 < tau[u] && (c0 + 64 + lane) != qg);
      while (m1) {
        int l = __builtin_ctzll(m1); m1 &= m1 - 1;
        float d = __shfl(d1, l);
        if (d < tau[u]) {
          insert1(ed[u], ei[u], d, c0 + 64 + l);
          if ((++cnt & 7) == 0) tau[u] = __shfl(ed[u], NSEL - 1);
        }
      }
      tau[u] = __shfl(ed[u], NSEL - 1);
    }
  }

  // ---------------- epilogue: exact re-rank of each query's 32 survivors ----------------
  // No LDS, no barriers: each wave's ed/ei[u] already covers all candidates.
#pragma unroll 1
  for (int u = 0; u < 4; ++u) {
    const int r32 = lane & 31;
    const int qloc = 4 * w + u;
    const int qg2 = q0 + qloc;
    int ci = __shfl(ei[u], r32);    // lanes 32..63 duplicate lanes 0..31 harmlessly

    const _Float16* qh = hb + (size_t)qg2 * CD;
    const _Float16* qlw = lb + (size_t)qg2 * CD;
    const _Float16* ch = hb + (size_t)ci * CD;
    const _Float16* cl = lb + (size_t)ci * CD;
    float dot = 0.f;
#pragma unroll 2   // LIMITED unroll: cap live registers (epilogue spill fix)
    for (int kc = 0; kc < CD / 8; ++kc) {
      f16x8 ah = *(const f16x8*)(qh + kc * 8);
      f16x8 al = *(const f16x8*)(qlw + kc * 8);
      f16x8 bh = *(const f16x8*)(ch + kc * 8);
      f16x8 bl = *(const f16x8*)(cl + kc * 8);
#pragma unroll
      for (int e = 0; e < 8; ++e) {
        float qv = fmaf((float)al[e], LOINV, (float)ah[e]);
        float cv = fmaf((float)bl[e], LOINV, (float)bh[e]);
        dot = fmaf(qv, cv, dot);
      }
    }
    float dex = (xq[qloc] + (-2.0f * dot)) + xb[ci];

    // bitonic sort 32 ascending by (dex, ci) within each 32-lane half
#pragma unroll
    for (int k = 2; k <= 32; k <<= 1) {
#pragma unroll
      for (int j2 = k >> 1; j2 >= 1; j2 >>= 1) {
        float od = __shfl_xor(dex, j2);
        int oi = __shfl_xor(ci, j2);
        bool lower = !(r32 & j2);
        bool up = ((r32 & k) == 0) || (k == 32);
        bool tt = (od < dex) || (od == dex && oi < ci);
        if (tt == (lower == up)) { dex = od; ci = oi; }
      }
    }
    if (lane < KNN)
      idxout[(size_t)(b * NQ + qg2) * KNN + lane] = ci;
  }
}

// ---------------- gather 20 neighbors (hi + lo/4096), max, write (B,C,N) ----------------
__global__ __launch_bounds__(256) void k_gather(const _Float16* __restrict__ vhi,
                                                const _Float16* __restrict__ vlo,
                                                const int* __restrict__ idx,
                                                float* __restrict__ out) {
  __shared__ float tile[CD][65];
  int blk = blockIdx.x;            // 256 blocks: 64 n's each
  int b = blk >> 7;
  int n0 = (blk & 127) * 64;
  int w = threadIdx.x >> 6, lane = threadIdx.x & 63;
  const _Float16* hb = vhi + (size_t)b * NQ * CD;
  const _Float16* lb = vlo + (size_t)b * NQ * CD;
  for (int s = 0; s < 16; ++s) {
    int nl = w * 16 + s;
    const int* id = idx + (size_t)(b * NQ + n0 + nl) * KNN;
    float ma = -3.0e38f, mb = -3.0e38f;  // cols 2*lane, 2*lane+1
#pragma unroll
    for (int j = 0; j < KNN; ++j) {
      size_t ro = (size_t)id[j] * CD + 2 * lane;
      f16x2 h = *(const f16x2*)(hb + ro);
      f16x2 l = *(const f16x2*)(lb + ro);
      ma = fmaxf(ma, fmaf((float)l[0], LOINV, (float)h[0]));
      mb = fmaxf(mb, fmaf((float)l[1], LOINV, (float)h[1]));
    }
    tile[2 * lane][nl] = ma;
    tile[2 * lane + 1][nl] = mb;
  }
  __syncthreads();
  float* ob = out + (size_t)b * CD * NQ;
  for (int i = 0; i < 32; ++i) {
    int e = threadIdx.x + i * 256;   // 128 c x 64 n
    int c = e >> 6, j = e & 63;
    ob[(size_t)c * NQ + n0 + j] = tile[c][j];
  }
}

extern "C" void kernel_launch(void* const* d_in, const int* in_sizes, int n_in,
                              void* d_out, int out_size, void* d_ws, size_t ws_size,
                              hipStream_t stream) {
  const float* x = (const float*)d_in[0];  // vertex_feat (B,C,N)
  size_t velems = (size_t)NB * NQ * CD;
  _Float16* vhi = (_Float16*)d_ws;                           // 4 MB
  _Float16* vlo = vhi + velems;                              // 4 MB
  float* xx = (float*)((char*)d_ws + velems * 4);            // 64 KB
  int* idx = (int*)((char*)xx + (size_t)NB * NQ * 4);        // 1.3 MB
  float* out = (float*)d_out;

  k_transpose<<<dim3(NB * 256 * 4), dim3(256), 0, stream>>>(x, vhi, vlo);
  k_xx<<<dim3(NQ / 256, NB), dim3(256), 0, stream>>>(x, xx);
  k_knn<<<dim3(NB * NQ / QB), dim3(512), 0, stream>>>(vhi, vlo, xx, idx);
  k_gather<<<dim3(NB * NQ / 64), dim3(256), 0, stream>>>(vhi, vlo, idx, out);
}